// Round 9
// baseline (81.870 us; speedup 1.0000x reference)
//
#include <hip/hip_runtime.h>
#include <hip/hip_bf16.h>
#include <math.h>

#define NB 8192
#define NG 8
#define NK 1024
#define ND 64
#define GD 512
#define MARGIN 2.5e-4f

typedef __attribute__((ext_vector_type(8))) short short8;
typedef __attribute__((ext_vector_type(4))) float f32x4;

// ws BYTE layout
#define WS_C2_OFF   0                          // f32[8192] exact c2, 32KB
#define WS_STG_OFF  32768                      // swizzled bf16 hi/lo staging, 8g*16it*16KB = 2MB
#define WS_CAND_OFF (32768 + 2097152)          // f32x4[65536], 1MB
#define WS_HIST_OFF (WS_CAND_OFF + 1048576)    // u32[1024]
#define WS_PART_OFF (WS_HIST_OFF + 4096)       // f32[16384]

typedef const __attribute__((address_space(1))) unsigned int glds_src_t;
typedef __attribute__((address_space(3))) unsigned int glds_dst_t;

__device__ inline void bsplit(float v, short& hs, short& ls) {
    __hip_bfloat16 h = __float2bfloat16(v);
    float hf = __bfloat162float(h);
    __hip_bfloat16 l = __float2bfloat16(v - hf);
    hs = *reinterpret_cast<short*>(&h);
    ls = *reinterpret_cast<short*>(&l);
}

__device__ inline float wredsum(float v) {
#pragma unroll
    for (int st = 1; st < 64; st <<= 1) v += __shfl_xor(v, st);
    return v;
}

// ---- prep: c2 exact; bf16 hi/lo codebook written as the XOR-swizzled staging image ----
// image: [g][it][hi-table 8KB | lo-table 8KB]; row r (code k&63) at r*128;
// logical 16B-granule j (d=8j..8j+7) stored at physical granule j^(r&7).
__global__ __launch_bounds__(256) void vq_prep(const float* __restrict__ cb,
                                               float* __restrict__ ws) {
    const int gid = blockIdx.x * 256 + threadIdx.x;   // code id 0..8191
    const int g  = gid >> 10, k = gid & 1023;
    const int it = k >> 6,   row = k & 63;
    const float* c = cb + (size_t)gid * ND;
    char* base = (char*)ws + WS_STG_OFF + (size_t)(g * 16 + it) * 16384 + row * 128;

    float a0 = 0.f, a1 = 0.f, a2 = 0.f, a3 = 0.f;
#pragma unroll
    for (int j = 0; j < 8; ++j) {                     // granule j: d = 8j..8j+7
        const float4 v0 = reinterpret_cast<const float4*>(c)[2 * j];
        const float4 v1 = reinterpret_cast<const float4*>(c)[2 * j + 1];
        a0 = fmaf(v0.x, v0.x, a0); a1 = fmaf(v0.y, v0.y, a1);
        a2 = fmaf(v0.z, v0.z, a2); a3 = fmaf(v0.w, v0.w, a3);
        a0 = fmaf(v1.x, v1.x, a0); a1 = fmaf(v1.y, v1.y, a1);
        a2 = fmaf(v1.z, v1.z, a2); a3 = fmaf(v1.w, v1.w, a3);
        short h0, l0, h1, l1, h2, l2, h3, l3;
        short h4, l4, h5, l5, h6, l6, h7, l7;
        bsplit(v0.x, h0, l0); bsplit(v0.y, h1, l1);
        bsplit(v0.z, h2, l2); bsplit(v0.w, h3, l3);
        bsplit(v1.x, h4, l4); bsplit(v1.y, h5, l5);
        bsplit(v1.z, h6, l6); bsplit(v1.w, h7, l7);
        short8 hs, ls;
        hs[0] = h0; hs[1] = h1; hs[2] = h2; hs[3] = h3;
        hs[4] = h4; hs[5] = h5; hs[6] = h6; hs[7] = h7;
        ls[0] = l0; ls[1] = l1; ls[2] = l2; ls[3] = l3;
        ls[4] = l4; ls[5] = l5; ls[6] = l6; ls[7] = l7;
        const int off = (j ^ (row & 7)) << 4;
        *reinterpret_cast<short8*>(base + off)        = hs;
        *reinterpret_cast<short8*>(base + 8192 + off) = ls;
    }
    ((float*)((char*)ws + WS_C2_OFF))[gid] = (a0 + a1) + (a2 + a3);
    if (gid < NK) ((unsigned*)((char*)ws + WS_HIST_OFF))[gid] = 0u;
}

// ---- score: triple-buffer depth-2 pipeline, counted vmcnt(4) + raw s_barrier ----
// numerics bit-identical to r8 (same loads, same MFMA order, same argmin).
__global__ __launch_bounds__(256, 3) void vq_score(const float* __restrict__ z,
                                                   float* __restrict__ ws) {
    __shared__ __align__(16) char smem[3][16384];
    const int tid  = threadIdx.x;
    const int w    = tid >> 6;
    const int lane = tid & 63;
    const int lo   = lane & 15, hi = lane >> 4;
    const int g    = blockIdx.y;
    const int rbase = blockIdx.x * 64 + w * 16;

    const char*  stg = (const char*)ws + WS_STG_OFF + (size_t)g * 16 * 16384;
    const float* c2g = (const float*)((const char*)ws + WS_C2_OFF) + g * NK;

    // A fragments (16 z-rows), bf16 hi/lo split. row=lo, d=ks*32+hi*8+e
    short8 Ah[2], Al[2];
#pragma unroll
    for (int ks = 0; ks < 2; ++ks) {
        const float* zp = z + (size_t)(rbase + lo) * GD + g * ND + ks * 32 + hi * 8;
        float vv[8];
        *reinterpret_cast<float4*>(&vv[0]) = reinterpret_cast<const float4*>(zp)[0];
        *reinterpret_cast<float4*>(&vv[4]) = reinterpret_cast<const float4*>(zp)[1];
#pragma unroll
        for (int e = 0; e < 8; ++e) {
            short hs, ls;
            bsplit(vv[e], hs, ls);
            Ah[ks][e] = hs;
            Al[ks][e] = ls;
        }
    }

    float best[4], b2[4];
    int   bk[4], k2[4];
#pragma unroll
    for (int q = 0; q < 4; ++q) { best[q] = 3.0e38f; b2[q] = 3.0e38f; bk[q] = 0; k2[q] = 0; }

    // swizzled read offsets (row&7 == lo&7 since row = n*16+lo)
    const int rowoff = lo * 128;
    const int swz0 = ((hi ^ (lo & 7)) << 4);
    const int swz1 = (((4 + hi) ^ (lo & 7)) << 4);
    const int stage_off = w * 4096 + lane * 16;       // this wave's staging quarter
    char* lds0 = &smem[0][0];

    const char* src = stg + stage_off;                // advances 16 KB per staged tile
    auto STAGE = [&](const char* s, unsigned dOff) {
#pragma unroll
        for (int i = 0; i < 4; ++i)
            __builtin_amdgcn_global_load_lds(
                (glds_src_t*)(const void*)(s + i * 1024),
                (glds_dst_t*)(void*)(lds0 + dOff + stage_off + i * 1024), 16, 0, 0);
    };

    // prologue: stage tiles 0,1 (depth 2); confirm tile 0; publish
    STAGE(src, 0u);      src += 16384;
    STAGE(src, 16384u);  src += 16384;
    asm volatile("s_waitcnt vmcnt(4)" ::: "memory");  // own tile-0 loads retired -> in LDS
    __builtin_amdgcn_s_barrier();                     // all waves' tile 0 visible
    __builtin_amdgcn_sched_barrier(0);

    unsigned cOff = 0u, sOff = 32768u;                // compute buf / stage target buf

#pragma unroll 1
    for (int it = 0; it < 16; ++it) {
        const int kb = it * 64;
        // c2v issued BEFORE the stage so the compiler's c2v wait can't drain the new stage
        float c2v[4];
#pragma unroll
        for (int n = 0; n < 4; ++n) c2v[n] = c2g[kb + n * 16 + lo];

        if (it < 14) { STAGE(src, sOff); src += 16384; }   // tile it+2, stays in flight

        const char* bufc = lds0 + cOff;
        f32x4 acc[4] = {{0.f,0.f,0.f,0.f},{0.f,0.f,0.f,0.f},{0.f,0.f,0.f,0.f},{0.f,0.f,0.f,0.f}};
#pragma unroll
        for (int p = 0; p < 8; ++p) {
            const int ks = p >> 2, n = p & 3;
            const int off = n * 2048 + rowoff + (ks ? swz1 : swz0);
            const short8 bhv = *reinterpret_cast<const short8*>(bufc + off);
            const short8 blv = *reinterpret_cast<const short8*>(bufc + 8192 + off);
            acc[n] = __builtin_amdgcn_mfma_f32_16x16x32_bf16(ks ? Ah[1] : Ah[0], bhv, acc[n], 0, 0, 0);
            acc[n] = __builtin_amdgcn_mfma_f32_16x16x32_bf16(ks ? Ah[1] : Ah[0], blv, acc[n], 0, 0, 0);
            acc[n] = __builtin_amdgcn_mfma_f32_16x16x32_bf16(ks ? Al[1] : Al[0], bhv, acc[n], 0, 0, 0);
        }

        // epilogue: score = c2 - 2*zc (z2 constant per row); frozen r3 arithmetic
#pragma unroll
        for (int n = 0; n < 4; ++n) {
            const int kv = kb + n * 16 + lo;
#pragma unroll
            for (int q = 0; q < 4; ++q) {
                const float s = fmaf(-2.0f, acc[n][q], c2v[n]);
                const bool lt  = s < best[q];
                const bool lt2 = s < b2[q];
                b2[q]   = lt ? best[q] : (lt2 ? s : b2[q]);
                k2[q]   = lt ? bk[q]   : (lt2 ? kv : k2[q]);
                best[q] = lt ? s : best[q];
                bk[q]   = lt ? kv : bk[q];
            }
        }

        // counted drain: retire tile it+1 (leave it+2 in flight), then publish
        if (it < 14)       asm volatile("s_waitcnt vmcnt(4)" ::: "memory");
        else if (it == 14) asm volatile("s_waitcnt vmcnt(0)" ::: "memory");
        if (it < 15) {
            __builtin_amdgcn_s_barrier();
            __builtin_amdgcn_sched_barrier(0);
        }
        cOff = (cOff == 32768u) ? 0u : cOff + 16384u;
        sOff = (sOff == 32768u) ? 0u : sOff + 16384u;
    }

    // butterfly over the 16 lo-lanes (frozen)
    f32x4* cand = (f32x4*)((char*)ws + WS_CAND_OFF);
#pragma unroll
    for (int q = 0; q < 4; ++q) {
        float pb = best[q], p2 = b2[q];
        int   kq = bk[q],   kq2 = k2[q];
#pragma unroll
        for (int st = 1; st < 16; st <<= 1) {
            const float ob  = __shfl_xor(pb, st);
            const int   obk = __shfl_xor(kq, st);
            const float ob2 = __shfl_xor(p2, st);
            const int   ok2 = __shfl_xor(kq2, st);
            const bool bet = (ob < pb) || (ob == pb && obk < kq);
            const float lb  = bet ? pb : ob;
            const int   lk  = bet ? kq : obk;
            const float wb2 = bet ? ob2 : p2;
            const int   wk2 = bet ? ok2 : kq2;
            const bool s2 = (lb < wb2) || (lb == wb2 && lk < wk2);
            p2  = s2 ? lb : wb2;
            kq2 = s2 ? lk : wk2;
            pb  = bet ? ob : pb;
            kq  = bet ? obk : kq;
        }
        if (lo == 0) {
            const int row = rbase + hi * 4 + q;
            f32x4 c;
            c[0] = pb;
            c[1] = __int_as_float(kq);
            c[2] = p2;
            c[3] = __int_as_float(kq2);
            cand[(size_t)g * NB + row] = c;
        }
    }
}

// ---------------- pick: window-2 exact rescue, write outputs ----------------
__global__ __launch_bounds__(256) void vq_pick(const float* __restrict__ z,
                                               const float* __restrict__ cb,
                                               float* __restrict__ out,
                                               float* __restrict__ ws) {
    const int tid  = threadIdx.x;
    const int wid  = tid >> 6;
    const int lane = tid & 63;
    const int unit = blockIdx.x * 4 + wid;     // 0..65535
    const int row  = unit >> 3;
    const int g    = unit & 7;

    const f32x4* cand = (const f32x4*)((const char*)ws + WS_CAND_OFF);
    const f32x4 cd = cand[(size_t)g * NB + row];
    const float bapp = cd[0];
    const int   bk   = __float_as_int(cd[1]);

    const float zd = z[(size_t)row * GD + g * ND + lane];
    int win = bk;

    if (cd[2] - bapp <= MARGIN) {              // wave-uniform rescue branch
        const int kalt = __float_as_int(cd[3]);
        const float* cgrp = cb + (size_t)g * NK * ND;
        const float* c2g  = (const float*)((const char*)ws + WS_C2_OFF) + g * NK;
        const float z2 = wredsum(zd * zd);
        const float c1 = cgrp[(size_t)bk * ND + lane];
        const float d1 = (z2 + c2g[bk]) - 2.0f * wredsum(zd * c1);
        const float c2 = cgrp[(size_t)kalt * ND + lane];
        const float d2 = (z2 + c2g[kalt]) - 2.0f * wredsum(zd * c2);
        if (d2 < d1 || (d2 == d1 && kalt < bk)) win = kalt;
    }

    const float cw = cb[((size_t)g * NK + win) * ND + lane];
    out[(size_t)row * GD + g * ND + lane] = zd + (cw - zd);

    const float e  = zd - cw;
    const float cs = wredsum(e * e);

    __shared__ float sh[4];
    if (lane == 0) {
        out[(size_t)NB * GD + (size_t)row * NG + g] = (float)win;
        atomicAdd((unsigned*)((char*)ws + WS_HIST_OFF) + win, 1u);
        sh[wid] = cs;
    }
    __syncthreads();
    if (tid == 0)
        ((float*)((char*)ws + WS_PART_OFF))[blockIdx.x] = (sh[0] + sh[1]) + (sh[2] + sh[3]);
}

// ---------------- finalize ----------------
__global__ __launch_bounds__(1024) void vq_final(const float* __restrict__ ws,
                                                 float* __restrict__ out) {
    const int t = threadIdx.x;
    __shared__ float se[1024];
    __shared__ float sc[1024];
    const unsigned cnt = ((const unsigned*)((const char*)ws + WS_HIST_OFF))[t];
    const float usage = (float)cnt * (1.0f / 65536.f);
    se[t] = -usage * logf(usage + 1e-10f);
    const float* part = (const float*)((const char*)ws + WS_PART_OFF);
    float s = 0.f;
#pragma unroll
    for (int i = 0; i < 16; ++i) s += part[t * 16 + i];
    sc[t] = s;
    __syncthreads();
    for (int st = 512; st > 0; st >>= 1) {
        if (t < st) {
            se[t] += se[t + st];
            sc[t] += sc[t + st];
        }
        __syncthreads();
    }
    if (t == 0) {
        float* scal = out + (size_t)NB * GD + (size_t)NB * NG;
        scal[0] = sc[0] * (1.0f / ((float)NB * NG * ND));  // commitment_loss
        scal[1] = 0.0f;                                    // codebook_loss
        scal[2] = se[0];                                   // entropy
        scal[3] = expf(se[0]);                             // perplexity
    }
}

extern "C" void kernel_launch(void* const* d_in, const int* in_sizes, int n_in,
                              void* d_out, int out_size, void* d_ws, size_t ws_size,
                              hipStream_t stream) {
    const float* z  = (const float*)d_in[0];
    const float* cb = (const float*)d_in[1];
    float* out = (float*)d_out;
    float* ws  = (float*)d_ws;

    hipLaunchKernelGGL(vq_prep,  dim3(32),     dim3(256),  0, stream, cb, ws);
    hipLaunchKernelGGL(vq_score, dim3(128, 8), dim3(256),  0, stream, z, ws);
    hipLaunchKernelGGL(vq_pick,  dim3(16384),  dim3(256),  0, stream, z, cb, out, ws);
    hipLaunchKernelGGL(vq_final, dim3(1),      dim3(1024), 0, stream, ws, out);
}

// Round 10
// 78.120 us; speedup vs baseline: 1.0480x; 1.0480x over previous
//
#include <hip/hip_runtime.h>
#include <hip/hip_bf16.h>
#include <math.h>

#define NB 8192
#define NG 8
#define NK 1024
#define ND 64
#define GD 512
#define MARGIN 2.5e-4f

typedef __attribute__((ext_vector_type(8))) short short8;
typedef __attribute__((ext_vector_type(4))) float f32x4;

// ws BYTE layout
#define WS_C2_OFF   0                          // f32[8192] exact c2, 32KB
#define WS_STG_OFF  32768                      // swizzled bf16 hi/lo staging, 8g*16it*16KB = 2MB
#define WS_CAND_OFF (32768 + 2097152)          // f32x4[65536], 1MB
#define WS_HIST_OFF (WS_CAND_OFF + 1048576)    // u32[1024]
#define WS_PART_OFF (WS_HIST_OFF + 4096)       // f32[16384]

typedef const __attribute__((address_space(1))) unsigned int glds_src_t;
typedef __attribute__((address_space(3))) unsigned int glds_dst_t;

__device__ inline void bsplit(float v, short& hs, short& ls) {
    __hip_bfloat16 h = __float2bfloat16(v);
    float hf = __bfloat162float(h);
    __hip_bfloat16 l = __float2bfloat16(v - hf);
    hs = *reinterpret_cast<short*>(&h);
    ls = *reinterpret_cast<short*>(&l);
}

__device__ inline float wredsum(float v) {
#pragma unroll
    for (int st = 1; st < 64; st <<= 1) v += __shfl_xor(v, st);
    return v;
}

// ---- prep: c2 exact; bf16 hi/lo codebook written as the XOR-swizzled staging image ----
// image: [g][it][hi-table 8KB | lo-table 8KB]; row r (code k&63) at r*128;
// logical 16B-granule j (d=8j..8j+7) stored at physical granule j^(r&7).
__global__ __launch_bounds__(256) void vq_prep(const float* __restrict__ cb,
                                               float* __restrict__ ws) {
    const int gid = blockIdx.x * 256 + threadIdx.x;   // code id 0..8191
    const int g  = gid >> 10, k = gid & 1023;
    const int it = k >> 6,   row = k & 63;
    const float* c = cb + (size_t)gid * ND;
    char* base = (char*)ws + WS_STG_OFF + (size_t)(g * 16 + it) * 16384 + row * 128;

    float a0 = 0.f, a1 = 0.f, a2 = 0.f, a3 = 0.f;
#pragma unroll
    for (int j = 0; j < 8; ++j) {                     // granule j: d = 8j..8j+7
        const float4 v0 = reinterpret_cast<const float4*>(c)[2 * j];
        const float4 v1 = reinterpret_cast<const float4*>(c)[2 * j + 1];
        a0 = fmaf(v0.x, v0.x, a0); a1 = fmaf(v0.y, v0.y, a1);
        a2 = fmaf(v0.z, v0.z, a2); a3 = fmaf(v0.w, v0.w, a3);
        a0 = fmaf(v1.x, v1.x, a0); a1 = fmaf(v1.y, v1.y, a1);
        a2 = fmaf(v1.z, v1.z, a2); a3 = fmaf(v1.w, v1.w, a3);
        short h0, l0, h1, l1, h2, l2, h3, l3;
        short h4, l4, h5, l5, h6, l6, h7, l7;
        bsplit(v0.x, h0, l0); bsplit(v0.y, h1, l1);
        bsplit(v0.z, h2, l2); bsplit(v0.w, h3, l3);
        bsplit(v1.x, h4, l4); bsplit(v1.y, h5, l5);
        bsplit(v1.z, h6, l6); bsplit(v1.w, h7, l7);
        short8 hs, ls;
        hs[0] = h0; hs[1] = h1; hs[2] = h2; hs[3] = h3;
        hs[4] = h4; hs[5] = h5; hs[6] = h6; hs[7] = h7;
        ls[0] = l0; ls[1] = l1; ls[2] = l2; ls[3] = l3;
        ls[4] = l4; ls[5] = l5; ls[6] = l6; ls[7] = l7;
        const int off = (j ^ (row & 7)) << 4;
        *reinterpret_cast<short8*>(base + off)        = hs;
        *reinterpret_cast<short8*>(base + 8192 + off) = ls;
    }
    ((float*)((char*)ws + WS_C2_OFF))[gid] = (a0 + a1) + (a2 + a3);
    if (gid < NK) ((unsigned*)((char*)ws + WS_HIST_OFF))[gid] = 0u;
}

// ---- score: m=2 (32 rows/wave), BK=128 (2 sub-tiles/iter, 8 barriers),
// ----        2-buffer syncthreads pipeline (r8 structure); frozen r3 numerics
__global__ __launch_bounds__(256, 2) void vq_score(const float* __restrict__ z,
                                                   float* __restrict__ ws) {
    __shared__ __align__(16) char smem[2][32768];
    const int tid  = threadIdx.x;
    const int w    = tid >> 6;
    const int lane = tid & 63;
    const int lo   = lane & 15, hi = lane >> 4;
    const int g    = blockIdx.y;
    const int rbase = blockIdx.x * 128 + w * 32;      // 32 rows per wave

    const char*  stg = (const char*)ws + WS_STG_OFF + (size_t)g * 16 * 16384;
    const float* c2g = (const float*)((const char*)ws + WS_C2_OFF) + g * NK;

    // A fragments (32 z-rows): m in {0,1}, row = rbase + m*16 + lo, d = ks*32+hi*8+e
    short8 Ah[2][2], Al[2][2];
#pragma unroll
    for (int m = 0; m < 2; ++m)
#pragma unroll
        for (int ks = 0; ks < 2; ++ks) {
            const float* zp = z + (size_t)(rbase + m * 16 + lo) * GD + g * ND + ks * 32 + hi * 8;
            float vv[8];
            *reinterpret_cast<float4*>(&vv[0]) = reinterpret_cast<const float4*>(zp)[0];
            *reinterpret_cast<float4*>(&vv[4]) = reinterpret_cast<const float4*>(zp)[1];
#pragma unroll
            for (int e = 0; e < 8; ++e) {
                short hs, ls;
                bsplit(vv[e], hs, ls);
                Ah[m][ks][e] = hs;
                Al[m][ks][e] = ls;
            }
        }

    // 8 argmin streams: slot s = m*4 + q
    float best[8], b2[8];
    int   bk[8], k2[8];
#pragma unroll
    for (int s = 0; s < 8; ++s) { best[s] = 3.0e38f; b2[s] = 3.0e38f; bk[s] = 0; k2[s] = 0; }

    // swizzled read offsets (row&7 == lo&7 since row = n*16+lo)
    const int rowoff = lo * 128;
    const int swz0 = ((hi ^ (lo & 7)) << 4);
    const int swz1 = (((4 + hi) ^ (lo & 7)) << 4);
    char* lds0 = &smem[0][0];

    // staging: 8 loads/wave cover a 32KB tile-pair; layout mirrors the image
    const char* src = stg;                            // advances 32KB per iter
    auto STAGE = [&](const char* s, unsigned dOff) {
#pragma unroll
        for (int i = 0; i < 8; ++i) {
            const int so = (i >> 2) * 16384 + w * 4096 + (i & 3) * 1024 + lane * 16;
            __builtin_amdgcn_global_load_lds(
                (glds_src_t*)(const void*)(s + so),
                (glds_dst_t*)(void*)(lds0 + dOff + so), 16, 0, 0);
        }
    };

    // prologue: stage tile-pair 0 into buf 0
    STAGE(src, 0u);
    src += 32768;
    __syncthreads();

#pragma unroll 1
    for (int it = 0; it < 8; ++it) {
        // c2 values issued BEFORE the stage (keeps compiler waits off the stage queue)
        float c2v[2][4];
#pragma unroll
        for (int t = 0; t < 2; ++t)
#pragma unroll
            for (int n = 0; n < 4; ++n)
                c2v[t][n] = c2g[it * 128 + t * 64 + n * 16 + lo];

        const unsigned cur = (unsigned)(it & 1) * 32768u;
        if (it < 7) { STAGE(src, cur ^ 32768u); src += 32768; }

        const char* bufc = lds0 + cur;
#pragma unroll
        for (int t = 0; t < 2; ++t) {
            f32x4 acc[2][4] = {};
#pragma unroll
            for (int p = 0; p < 8; ++p) {
                const int ks = p >> 2, n = p & 3;
                const int off = t * 16384 + n * 2048 + rowoff + (ks ? swz1 : swz0);
                const short8 bhv = *reinterpret_cast<const short8*>(bufc + off);
                const short8 blv = *reinterpret_cast<const short8*>(bufc + 8192 + off);
#pragma unroll
                for (int m = 0; m < 2; ++m) {
                    acc[m][n] = __builtin_amdgcn_mfma_f32_16x16x32_bf16(ks ? Ah[m][1] : Ah[m][0], bhv, acc[m][n], 0, 0, 0);
                    acc[m][n] = __builtin_amdgcn_mfma_f32_16x16x32_bf16(ks ? Ah[m][1] : Ah[m][0], blv, acc[m][n], 0, 0, 0);
                    acc[m][n] = __builtin_amdgcn_mfma_f32_16x16x32_bf16(ks ? Al[m][1] : Al[m][0], bhv, acc[m][n], 0, 0, 0);
                }
            }

            // epilogue: score = c2 - 2*zc (z2 constant per row); frozen r3 arithmetic
#pragma unroll
            for (int n = 0; n < 4; ++n) {
                const int kv = it * 128 + t * 64 + n * 16 + lo;
#pragma unroll
                for (int m = 0; m < 2; ++m)
#pragma unroll
                    for (int q = 0; q < 4; ++q) {
                        const int sidx = m * 4 + q;
                        const float s = fmaf(-2.0f, acc[m][n][q], c2v[t][n]);
                        const bool lt  = s < best[sidx];
                        const bool lt2 = s < b2[sidx];
                        b2[sidx]   = lt ? best[sidx] : (lt2 ? s : b2[sidx]);
                        k2[sidx]   = lt ? bk[sidx]   : (lt2 ? kv : k2[sidx]);
                        best[sidx] = lt ? s : best[sidx];
                        bk[sidx]   = lt ? kv : bk[sidx];
                    }
            }
        }
        __syncthreads();              // drains own stage loads + protects buffer reuse
    }

    // butterfly over the 16 lo-lanes (frozen), 8 streams
    f32x4* cand = (f32x4*)((char*)ws + WS_CAND_OFF);
#pragma unroll
    for (int s = 0; s < 8; ++s) {
        const int m = s >> 2, q = s & 3;
        float pb = best[s], p2 = b2[s];
        int   kq = bk[s],   kq2 = k2[s];
#pragma unroll
        for (int st = 1; st < 16; st <<= 1) {
            const float ob  = __shfl_xor(pb, st);
            const int   obk = __shfl_xor(kq, st);
            const float ob2 = __shfl_xor(p2, st);
            const int   ok2 = __shfl_xor(kq2, st);
            const bool bet = (ob < pb) || (ob == pb && obk < kq);
            const float lb  = bet ? pb : ob;
            const int   lk  = bet ? kq : obk;
            const float wb2 = bet ? ob2 : p2;
            const int   wk2 = bet ? ok2 : kq2;
            const bool s2 = (lb < wb2) || (lb == wb2 && lk < wk2);
            p2  = s2 ? lb : wb2;
            kq2 = s2 ? lk : wk2;
            pb  = bet ? ob : pb;
            kq  = bet ? obk : kq;
        }
        if (lo == 0) {
            const int row = rbase + m * 16 + hi * 4 + q;
            f32x4 c;
            c[0] = pb;
            c[1] = __int_as_float(kq);
            c[2] = p2;
            c[3] = __int_as_float(kq2);
            cand[(size_t)g * NB + row] = c;
        }
    }
}

// ---------------- pick: window-2 exact rescue, write outputs ----------------
__global__ __launch_bounds__(256) void vq_pick(const float* __restrict__ z,
                                               const float* __restrict__ cb,
                                               float* __restrict__ out,
                                               float* __restrict__ ws) {
    const int tid  = threadIdx.x;
    const int wid  = tid >> 6;
    const int lane = tid & 63;
    const int unit = blockIdx.x * 4 + wid;     // 0..65535
    const int row  = unit >> 3;
    const int g    = unit & 7;

    const f32x4* cand = (const f32x4*)((const char*)ws + WS_CAND_OFF);
    const f32x4 cd = cand[(size_t)g * NB + row];
    const float bapp = cd[0];
    const int   bk   = __float_as_int(cd[1]);

    const float zd = z[(size_t)row * GD + g * ND + lane];
    int win = bk;

    if (cd[2] - bapp <= MARGIN) {              // wave-uniform rescue branch
        const int kalt = __float_as_int(cd[3]);
        const float* cgrp = cb + (size_t)g * NK * ND;
        const float* c2g  = (const float*)((const char*)ws + WS_C2_OFF) + g * NK;
        const float z2 = wredsum(zd * zd);
        const float c1 = cgrp[(size_t)bk * ND + lane];
        const float d1 = (z2 + c2g[bk]) - 2.0f * wredsum(zd * c1);
        const float c2 = cgrp[(size_t)kalt * ND + lane];
        const float d2 = (z2 + c2g[kalt]) - 2.0f * wredsum(zd * c2);
        if (d2 < d1 || (d2 == d1 && kalt < bk)) win = kalt;
    }

    const float cw = cb[((size_t)g * NK + win) * ND + lane];
    out[(size_t)row * GD + g * ND + lane] = zd + (cw - zd);

    const float e  = zd - cw;
    const float cs = wredsum(e * e);

    __shared__ float sh[4];
    if (lane == 0) {
        out[(size_t)NB * GD + (size_t)row * NG + g] = (float)win;
        atomicAdd((unsigned*)((char*)ws + WS_HIST_OFF) + win, 1u);
        sh[wid] = cs;
    }
    __syncthreads();
    if (tid == 0)
        ((float*)((char*)ws + WS_PART_OFF))[blockIdx.x] = (sh[0] + sh[1]) + (sh[2] + sh[3]);
}

// ---------------- finalize ----------------
__global__ __launch_bounds__(1024) void vq_final(const float* __restrict__ ws,
                                                 float* __restrict__ out) {
    const int t = threadIdx.x;
    __shared__ float se[1024];
    __shared__ float sc[1024];
    const unsigned cnt = ((const unsigned*)((const char*)ws + WS_HIST_OFF))[t];
    const float usage = (float)cnt * (1.0f / 65536.f);
    se[t] = -usage * logf(usage + 1e-10f);
    const float* part = (const float*)((const char*)ws + WS_PART_OFF);
    float s = 0.f;
#pragma unroll
    for (int i = 0; i < 16; ++i) s += part[t * 16 + i];
    sc[t] = s;
    __syncthreads();
    for (int st = 512; st > 0; st >>= 1) {
        if (t < st) {
            se[t] += se[t + st];
            sc[t] += sc[t + st];
        }
        __syncthreads();
    }
    if (t == 0) {
        float* scal = out + (size_t)NB * GD + (size_t)NB * NG;
        scal[0] = sc[0] * (1.0f / ((float)NB * NG * ND));  // commitment_loss
        scal[1] = 0.0f;                                    // codebook_loss
        scal[2] = se[0];                                   // entropy
        scal[3] = expf(se[0]);                             // perplexity
    }
}

extern "C" void kernel_launch(void* const* d_in, const int* in_sizes, int n_in,
                              void* d_out, int out_size, void* d_ws, size_t ws_size,
                              hipStream_t stream) {
    const float* z  = (const float*)d_in[0];
    const float* cb = (const float*)d_in[1];
    float* out = (float*)d_out;
    float* ws  = (float*)d_ws;

    hipLaunchKernelGGL(vq_prep,  dim3(32),    dim3(256),  0, stream, cb, ws);
    hipLaunchKernelGGL(vq_score, dim3(64, 8), dim3(256),  0, stream, z, ws);
    hipLaunchKernelGGL(vq_pick,  dim3(16384), dim3(256),  0, stream, z, cb, out, ws);
    hipLaunchKernelGGL(vq_final, dim3(1),     dim3(1024), 0, stream, ws, out);
}

// Round 11
// 74.450 us; speedup vs baseline: 1.0997x; 1.0493x over previous
//
#include <hip/hip_runtime.h>
#include <hip/hip_bf16.h>
#include <math.h>

#define NB 8192
#define NG 8
#define NK 1024
#define ND 64
#define GD 512
#define MARGIN 2.5e-4f

typedef __attribute__((ext_vector_type(8))) short short8;
typedef __attribute__((ext_vector_type(4))) float f32x4;

// ws BYTE layout
#define WS_C2_OFF   0                          // f32[8192] exact c2, 32KB
#define WS_STG_OFF  32768                      // swizzled bf16 hi/lo staging, 8g*16it*16KB = 2MB
#define WS_CAND_OFF (32768 + 2097152)          // f32x4[65536], 1MB
#define WS_HIST_OFF (WS_CAND_OFF + 1048576)    // u32[1024]
#define WS_PART_OFF (WS_HIST_OFF + 4096)       // f32[16384]

typedef const __attribute__((address_space(1))) unsigned int glds_src_t;
typedef __attribute__((address_space(3))) unsigned int glds_dst_t;

__device__ inline void bsplit(float v, short& hs, short& ls) {
    __hip_bfloat16 h = __float2bfloat16(v);
    float hf = __bfloat162float(h);
    __hip_bfloat16 l = __float2bfloat16(v - hf);
    hs = *reinterpret_cast<short*>(&h);
    ls = *reinterpret_cast<short*>(&l);
}

__device__ inline float wredsum(float v) {
#pragma unroll
    for (int st = 1; st < 64; st <<= 1) v += __shfl_xor(v, st);
    return v;
}

// ---- prep: c2 exact; bf16 hi/lo codebook written as the XOR-swizzled staging image ----
// image: [g][it][hi-table 8KB | lo-table 8KB]; row r (code k&63) at r*128;
// logical 16B-granule j (d=8j..8j+7) stored at physical granule j^(r&7).
// spread over 128 blocks x 64 threads for CU coverage.
__global__ __launch_bounds__(64) void vq_prep(const float* __restrict__ cb,
                                              float* __restrict__ ws) {
    const int gid = blockIdx.x * 64 + threadIdx.x;    // code id 0..8191
    const int g  = gid >> 10, k = gid & 1023;
    const int it = k >> 6,   row = k & 63;
    const float* c = cb + (size_t)gid * ND;
    char* base = (char*)ws + WS_STG_OFF + (size_t)(g * 16 + it) * 16384 + row * 128;

    float a0 = 0.f, a1 = 0.f, a2 = 0.f, a3 = 0.f;
#pragma unroll
    for (int j = 0; j < 8; ++j) {                     // granule j: d = 8j..8j+7
        const float4 v0 = reinterpret_cast<const float4*>(c)[2 * j];
        const float4 v1 = reinterpret_cast<const float4*>(c)[2 * j + 1];
        a0 = fmaf(v0.x, v0.x, a0); a1 = fmaf(v0.y, v0.y, a1);
        a2 = fmaf(v0.z, v0.z, a2); a3 = fmaf(v0.w, v0.w, a3);
        a0 = fmaf(v1.x, v1.x, a0); a1 = fmaf(v1.y, v1.y, a1);
        a2 = fmaf(v1.z, v1.z, a2); a3 = fmaf(v1.w, v1.w, a3);
        short h0, l0, h1, l1, h2, l2, h3, l3;
        short h4, l4, h5, l5, h6, l6, h7, l7;
        bsplit(v0.x, h0, l0); bsplit(v0.y, h1, l1);
        bsplit(v0.z, h2, l2); bsplit(v0.w, h3, l3);
        bsplit(v1.x, h4, l4); bsplit(v1.y, h5, l5);
        bsplit(v1.z, h6, l6); bsplit(v1.w, h7, l7);
        short8 hs, ls;
        hs[0] = h0; hs[1] = h1; hs[2] = h2; hs[3] = h3;
        hs[4] = h4; hs[5] = h5; hs[6] = h6; hs[7] = h7;
        ls[0] = l0; ls[1] = l1; ls[2] = l2; ls[3] = l3;
        ls[4] = l4; ls[5] = l5; ls[6] = l6; ls[7] = l7;
        const int off = (j ^ (row & 7)) << 4;
        *reinterpret_cast<short8*>(base + off)        = hs;
        *reinterpret_cast<short8*>(base + 8192 + off) = ls;
    }
    ((float*)((char*)ws + WS_C2_OFF))[gid] = (a0 + a1) + (a2 + a3);
    if (gid < NK) ((unsigned*)((char*)ws + WS_HIST_OFF))[gid] = 0u;
}

// ---- score: m=2, BK=128, 2-buffer syncthreads pipeline; de-chained MFMA:
// ----        batch 8 B-loads per ks, then term-major MFMAs over 8 indep accs.
// ----        Per-acc accumulation order unchanged (hh,hl,lh per ks) => bit-identical.
__global__ __launch_bounds__(256, 2) void vq_score(const float* __restrict__ z,
                                                   float* __restrict__ ws) {
    __shared__ __align__(16) char smem[2][32768];
    const int tid  = threadIdx.x;
    const int w    = tid >> 6;
    const int lane = tid & 63;
    const int lo   = lane & 15, hi = lane >> 4;
    const int g    = blockIdx.y;
    const int rbase = blockIdx.x * 128 + w * 32;      // 32 rows per wave

    const char*  stg = (const char*)ws + WS_STG_OFF + (size_t)g * 16 * 16384;
    const float* c2g = (const float*)((const char*)ws + WS_C2_OFF) + g * NK;

    // A fragments (32 z-rows): m in {0,1}, row = rbase + m*16 + lo, d = ks*32+hi*8+e
    short8 Ah[2][2], Al[2][2];
#pragma unroll
    for (int m = 0; m < 2; ++m)
#pragma unroll
        for (int ks = 0; ks < 2; ++ks) {
            const float* zp = z + (size_t)(rbase + m * 16 + lo) * GD + g * ND + ks * 32 + hi * 8;
            float vv[8];
            *reinterpret_cast<float4*>(&vv[0]) = reinterpret_cast<const float4*>(zp)[0];
            *reinterpret_cast<float4*>(&vv[4]) = reinterpret_cast<const float4*>(zp)[1];
#pragma unroll
            for (int e = 0; e < 8; ++e) {
                short hs, ls;
                bsplit(vv[e], hs, ls);
                Ah[m][ks][e] = hs;
                Al[m][ks][e] = ls;
            }
        }

    // 8 argmin streams: slot s = m*4 + q (frozen r3 numerics)
    float best[8], b2[8];
    int   bk[8], k2[8];
#pragma unroll
    for (int s = 0; s < 8; ++s) { best[s] = 3.0e38f; b2[s] = 3.0e38f; bk[s] = 0; k2[s] = 0; }

    // swizzled read offsets (row&7 == lo&7 since row = n*16+lo)
    const int rowoff = lo * 128;
    const int swz0 = ((hi ^ (lo & 7)) << 4);
    const int swz1 = (((4 + hi) ^ (lo & 7)) << 4);
    char* lds0 = &smem[0][0];

    // staging: 8 loads/wave cover a 32KB tile-pair; layout mirrors the image
    const char* src = stg;                            // advances 32KB per iter
    auto STAGE = [&](const char* s, unsigned dOff) {
#pragma unroll
        for (int i = 0; i < 8; ++i) {
            const int so = (i >> 2) * 16384 + w * 4096 + (i & 3) * 1024 + lane * 16;
            __builtin_amdgcn_global_load_lds(
                (glds_src_t*)(const void*)(s + so),
                (glds_dst_t*)(void*)(lds0 + dOff + so), 16, 0, 0);
        }
    };

    // prologue: stage tile-pair 0 into buf 0
    STAGE(src, 0u);
    src += 32768;
    __syncthreads();

#pragma unroll 1
    for (int it = 0; it < 8; ++it) {
        // c2 values issued BEFORE the stage (keeps compiler waits off the stage queue)
        float c2v[2][4];
#pragma unroll
        for (int t = 0; t < 2; ++t)
#pragma unroll
            for (int n = 0; n < 4; ++n)
                c2v[t][n] = c2g[it * 128 + t * 64 + n * 16 + lo];

        const unsigned cur = (unsigned)(it & 1) * 32768u;
        if (it < 7) { STAGE(src, cur ^ 32768u); src += 32768; }

        const char* bufc = lds0 + cur;
#pragma unroll
        for (int t = 0; t < 2; ++t) {
            f32x4 acc[2][4] = {};
#pragma unroll
            for (int ks = 0; ks < 2; ++ks) {
                // batch: 8 ds_read_b128 up front -> one lgkm wait, then pure MFMA
                short8 bh[4], bl[4];
#pragma unroll
                for (int n = 0; n < 4; ++n) {
                    const int off = t * 16384 + n * 2048 + rowoff + (ks ? swz1 : swz0);
                    bh[n] = *reinterpret_cast<const short8*>(bufc + off);
                    bl[n] = *reinterpret_cast<const short8*>(bufc + 8192 + off);
                }
                // term-major: 8 independent acc chains per term -> throughput issue
#pragma unroll
                for (int n = 0; n < 4; ++n)
#pragma unroll
                    for (int m = 0; m < 2; ++m)
                        acc[m][n] = __builtin_amdgcn_mfma_f32_16x16x32_bf16(
                            ks ? Ah[m][1] : Ah[m][0], bh[n], acc[m][n], 0, 0, 0);
#pragma unroll
                for (int n = 0; n < 4; ++n)
#pragma unroll
                    for (int m = 0; m < 2; ++m)
                        acc[m][n] = __builtin_amdgcn_mfma_f32_16x16x32_bf16(
                            ks ? Ah[m][1] : Ah[m][0], bl[n], acc[m][n], 0, 0, 0);
#pragma unroll
                for (int n = 0; n < 4; ++n)
#pragma unroll
                    for (int m = 0; m < 2; ++m)
                        acc[m][n] = __builtin_amdgcn_mfma_f32_16x16x32_bf16(
                            ks ? Al[m][1] : Al[m][0], bh[n], acc[m][n], 0, 0, 0);
            }

            // epilogue: score = c2 - 2*zc (z2 constant per row); frozen r3 arithmetic
#pragma unroll
            for (int n = 0; n < 4; ++n) {
                const int kv = it * 128 + t * 64 + n * 16 + lo;
#pragma unroll
                for (int m = 0; m < 2; ++m)
#pragma unroll
                    for (int q = 0; q < 4; ++q) {
                        const int sidx = m * 4 + q;
                        const float s = fmaf(-2.0f, acc[m][n][q], c2v[t][n]);
                        const bool lt  = s < best[sidx];
                        const bool lt2 = s < b2[sidx];
                        b2[sidx]   = lt ? best[sidx] : (lt2 ? s : b2[sidx]);
                        k2[sidx]   = lt ? bk[sidx]   : (lt2 ? kv : k2[sidx]);
                        best[sidx] = lt ? s : best[sidx];
                        bk[sidx]   = lt ? kv : bk[sidx];
                    }
            }
        }
        __syncthreads();              // drains own stage loads + protects buffer reuse
    }

    // butterfly over the 16 lo-lanes (frozen), 8 streams
    f32x4* cand = (f32x4*)((char*)ws + WS_CAND_OFF);
#pragma unroll
    for (int s = 0; s < 8; ++s) {
        const int m = s >> 2, q = s & 3;
        float pb = best[s], p2 = b2[s];
        int   kq = bk[s],   kq2 = k2[s];
#pragma unroll
        for (int st = 1; st < 16; st <<= 1) {
            const float ob  = __shfl_xor(pb, st);
            const int   obk = __shfl_xor(kq, st);
            const float ob2 = __shfl_xor(p2, st);
            const int   ok2 = __shfl_xor(kq2, st);
            const bool bet = (ob < pb) || (ob == pb && obk < kq);
            const float lb  = bet ? pb : ob;
            const int   lk  = bet ? kq : obk;
            const float wb2 = bet ? ob2 : p2;
            const int   wk2 = bet ? ok2 : kq2;
            const bool s2 = (lb < wb2) || (lb == wb2 && lk < wk2);
            p2  = s2 ? lb : wb2;
            kq2 = s2 ? lk : wk2;
            pb  = bet ? ob : pb;
            kq  = bet ? obk : kq;
        }
        if (lo == 0) {
            const int row = rbase + m * 16 + hi * 4 + q;
            f32x4 c;
            c[0] = pb;
            c[1] = __int_as_float(kq);
            c[2] = p2;
            c[3] = __int_as_float(kq2);
            cand[(size_t)g * NB + row] = c;
        }
    }
}

// ---------------- pick: window-2 exact rescue, write outputs ----------------
__global__ __launch_bounds__(256) void vq_pick(const float* __restrict__ z,
                                               const float* __restrict__ cb,
                                               float* __restrict__ out,
                                               float* __restrict__ ws) {
    const int tid  = threadIdx.x;
    const int wid  = tid >> 6;
    const int lane = tid & 63;
    const int unit = blockIdx.x * 4 + wid;     // 0..65535
    const int row  = unit >> 3;
    const int g    = unit & 7;

    const f32x4* cand = (const f32x4*)((const char*)ws + WS_CAND_OFF);
    const f32x4 cd = cand[(size_t)g * NB + row];
    const float bapp = cd[0];
    const int   bk   = __float_as_int(cd[1]);

    const float zd = z[(size_t)row * GD + g * ND + lane];
    int win = bk;

    if (cd[2] - bapp <= MARGIN) {              // wave-uniform rescue branch
        const int kalt = __float_as_int(cd[3]);
        const float* cgrp = cb + (size_t)g * NK * ND;
        const float* c2g  = (const float*)((const char*)ws + WS_C2_OFF) + g * NK;
        const float z2 = wredsum(zd * zd);
        const float c1 = cgrp[(size_t)bk * ND + lane];
        const float d1 = (z2 + c2g[bk]) - 2.0f * wredsum(zd * c1);
        const float c2 = cgrp[(size_t)kalt * ND + lane];
        const float d2 = (z2 + c2g[kalt]) - 2.0f * wredsum(zd * c2);
        if (d2 < d1 || (d2 == d1 && kalt < bk)) win = kalt;
    }

    const float cw = cb[((size_t)g * NK + win) * ND + lane];
    out[(size_t)row * GD + g * ND + lane] = zd + (cw - zd);

    const float e  = zd - cw;
    const float cs = wredsum(e * e);

    __shared__ float sh[4];
    if (lane == 0) {
        out[(size_t)NB * GD + (size_t)row * NG + g] = (float)win;
        atomicAdd((unsigned*)((char*)ws + WS_HIST_OFF) + win, 1u);
        sh[wid] = cs;
    }
    __syncthreads();
    if (tid == 0)
        ((float*)((char*)ws + WS_PART_OFF))[blockIdx.x] = (sh[0] + sh[1]) + (sh[2] + sh[3]);
}

// ---------------- finalize ----------------
__global__ __launch_bounds__(1024) void vq_final(const float* __restrict__ ws,
                                                 float* __restrict__ out) {
    const int t = threadIdx.x;
    __shared__ float se[1024];
    __shared__ float sc[1024];
    const unsigned cnt = ((const unsigned*)((const char*)ws + WS_HIST_OFF))[t];
    const float usage = (float)cnt * (1.0f / 65536.f);
    se[t] = -usage * logf(usage + 1e-10f);
    const float* part = (const float*)((const char*)ws + WS_PART_OFF);
    float s = 0.f;
#pragma unroll
    for (int i = 0; i < 16; ++i) s += part[t + 1024 * i];   // coalesced strided loads
    sc[t] = s;
    __syncthreads();
    for (int st = 512; st > 0; st >>= 1) {
        if (t < st) {
            se[t] += se[t + st];
            sc[t] += sc[t + st];
        }
        __syncthreads();
    }
    if (t == 0) {
        float* scal = out + (size_t)NB * GD + (size_t)NB * NG;
        scal[0] = sc[0] * (1.0f / ((float)NB * NG * ND));  // commitment_loss
        scal[1] = 0.0f;                                    // codebook_loss
        scal[2] = se[0];                                   // entropy
        scal[3] = expf(se[0]);                             // perplexity
    }
}

extern "C" void kernel_launch(void* const* d_in, const int* in_sizes, int n_in,
                              void* d_out, int out_size, void* d_ws, size_t ws_size,
                              hipStream_t stream) {
    const float* z  = (const float*)d_in[0];
    const float* cb = (const float*)d_in[1];
    float* out = (float*)d_out;
    float* ws  = (float*)d_ws;

    hipLaunchKernelGGL(vq_prep,  dim3(128),   dim3(64),   0, stream, cb, ws);
    hipLaunchKernelGGL(vq_score, dim3(64, 8), dim3(256),  0, stream, z, ws);
    hipLaunchKernelGGL(vq_pick,  dim3(16384), dim3(256),  0, stream, z, cb, out, ws);
    hipLaunchKernelGGL(vq_final, dim3(1),     dim3(1024), 0, stream, ws, out);
}

// Round 12
// 64.567 us; speedup vs baseline: 1.2680x; 1.1531x over previous
//
#include <hip/hip_runtime.h>
#include <hip/hip_bf16.h>
#include <math.h>

#define NB 8192
#define NG 8
#define NK 1024
#define ND 64
#define GD 512
#define MARGIN 2.5e-4f

typedef __attribute__((ext_vector_type(8))) short short8;
typedef __attribute__((ext_vector_type(4))) float f32x4;

// ws BYTE layout
#define WS_C2_OFF   0                          // f32[8192] exact c2, 32KB
#define WS_STG_OFF  32768                      // swizzled bf16 hi/lo staging, 8g*16it*16KB = 2MB
#define WS_HIST_OFF (32768 + 2097152 + 1048576) // u32[1024] (kept at old offset)
#define WS_PART_OFF (WS_HIST_OFF + 4096)       // f32[512]

typedef const __attribute__((address_space(1))) unsigned int glds_src_t;
typedef __attribute__((address_space(3))) unsigned int glds_dst_t;

__device__ inline void bsplit(float v, short& hs, short& ls) {
    __hip_bfloat16 h = __float2bfloat16(v);
    float hf = __bfloat162float(h);
    __hip_bfloat16 l = __float2bfloat16(v - hf);
    hs = *reinterpret_cast<short*>(&h);
    ls = *reinterpret_cast<short*>(&l);
}

__device__ inline float wredsum(float v) {
#pragma unroll
    for (int st = 1; st < 64; st <<= 1) v += __shfl_xor(v, st);
    return v;
}

// ---- prep: c2 exact; bf16 hi/lo codebook written as the XOR-swizzled staging image ----
__global__ __launch_bounds__(64) void vq_prep(const float* __restrict__ cb,
                                              float* __restrict__ ws) {
    const int gid = blockIdx.x * 64 + threadIdx.x;    // code id 0..8191
    const int g  = gid >> 10, k = gid & 1023;
    const int it = k >> 6,   row = k & 63;
    const float* c = cb + (size_t)gid * ND;
    char* base = (char*)ws + WS_STG_OFF + (size_t)(g * 16 + it) * 16384 + row * 128;

    float a0 = 0.f, a1 = 0.f, a2 = 0.f, a3 = 0.f;
#pragma unroll
    for (int j = 0; j < 8; ++j) {                     // granule j: d = 8j..8j+7
        const float4 v0 = reinterpret_cast<const float4*>(c)[2 * j];
        const float4 v1 = reinterpret_cast<const float4*>(c)[2 * j + 1];
        a0 = fmaf(v0.x, v0.x, a0); a1 = fmaf(v0.y, v0.y, a1);
        a2 = fmaf(v0.z, v0.z, a2); a3 = fmaf(v0.w, v0.w, a3);
        a0 = fmaf(v1.x, v1.x, a0); a1 = fmaf(v1.y, v1.y, a1);
        a2 = fmaf(v1.z, v1.z, a2); a3 = fmaf(v1.w, v1.w, a3);
        short h0, l0, h1, l1, h2, l2, h3, l3;
        short h4, l4, h5, l5, h6, l6, h7, l7;
        bsplit(v0.x, h0, l0); bsplit(v0.y, h1, l1);
        bsplit(v0.z, h2, l2); bsplit(v0.w, h3, l3);
        bsplit(v1.x, h4, l4); bsplit(v1.y, h5, l5);
        bsplit(v1.z, h6, l6); bsplit(v1.w, h7, l7);
        short8 hs, ls;
        hs[0] = h0; hs[1] = h1; hs[2] = h2; hs[3] = h3;
        hs[4] = h4; hs[5] = h5; hs[6] = h6; hs[7] = h7;
        ls[0] = l0; ls[1] = l1; ls[2] = l2; ls[3] = l3;
        ls[4] = l4; ls[5] = l5; ls[6] = l6; ls[7] = l7;
        const int off = (j ^ (row & 7)) << 4;
        *reinterpret_cast<short8*>(base + off)        = hs;
        *reinterpret_cast<short8*>(base + 8192 + off) = ls;
    }
    ((float*)((char*)ws + WS_C2_OFF))[gid] = (a0 + a1) + (a2 + a3);
    if (gid < NK) ((unsigned*)((char*)ws + WS_HIST_OFF))[gid] = 0u;
}

// ---- score+pick fused: frozen k-loop (r11), then in-kernel rescue/gather/write ----
__global__ __launch_bounds__(256, 2) void vq_score(const float* __restrict__ z,
                                                   const float* __restrict__ cb,
                                                   float* __restrict__ out,
                                                   float* __restrict__ ws) {
    __shared__ __align__(16) char smem[2][32768];
    __shared__ int winfo[4][32];
    const int tid  = threadIdx.x;
    const int w    = tid >> 6;
    const int lane = tid & 63;
    const int lo   = lane & 15, hi = lane >> 4;
    const int g    = blockIdx.y;
    const int rbase = blockIdx.x * 128 + w * 32;      // 32 rows per wave

    const char*  stg = (const char*)ws + WS_STG_OFF + (size_t)g * 16 * 16384;
    const float* c2g = (const float*)((const char*)ws + WS_C2_OFF) + g * NK;

    // A fragments (32 z-rows): m in {0,1}, row = rbase + m*16 + lo, d = ks*32+hi*8+e
    short8 Ah[2][2], Al[2][2];
#pragma unroll
    for (int m = 0; m < 2; ++m)
#pragma unroll
        for (int ks = 0; ks < 2; ++ks) {
            const float* zp = z + (size_t)(rbase + m * 16 + lo) * GD + g * ND + ks * 32 + hi * 8;
            float vv[8];
            *reinterpret_cast<float4*>(&vv[0]) = reinterpret_cast<const float4*>(zp)[0];
            *reinterpret_cast<float4*>(&vv[4]) = reinterpret_cast<const float4*>(zp)[1];
#pragma unroll
            for (int e = 0; e < 8; ++e) {
                short hs, ls;
                bsplit(vv[e], hs, ls);
                Ah[m][ks][e] = hs;
                Al[m][ks][e] = ls;
            }
        }

    // 8 argmin streams: slot s = m*4 + q (frozen r3 numerics)
    float best[8], b2[8];
    int   bk[8], k2[8];
#pragma unroll
    for (int s = 0; s < 8; ++s) { best[s] = 3.0e38f; b2[s] = 3.0e38f; bk[s] = 0; k2[s] = 0; }

    const int rowoff = lo * 128;
    const int swz0 = ((hi ^ (lo & 7)) << 4);
    const int swz1 = (((4 + hi) ^ (lo & 7)) << 4);
    char* lds0 = &smem[0][0];

    const char* src = stg;                            // advances 32KB per iter
    auto STAGE = [&](const char* s, unsigned dOff) {
#pragma unroll
        for (int i = 0; i < 8; ++i) {
            const int so = (i >> 2) * 16384 + w * 4096 + (i & 3) * 1024 + lane * 16;
            __builtin_amdgcn_global_load_lds(
                (glds_src_t*)(const void*)(s + so),
                (glds_dst_t*)(void*)(lds0 + dOff + so), 16, 0, 0);
        }
    };

    STAGE(src, 0u);
    src += 32768;
    __syncthreads();

#pragma unroll 1
    for (int it = 0; it < 8; ++it) {
        float c2v[2][4];
#pragma unroll
        for (int t = 0; t < 2; ++t)
#pragma unroll
            for (int n = 0; n < 4; ++n)
                c2v[t][n] = c2g[it * 128 + t * 64 + n * 16 + lo];

        const unsigned cur = (unsigned)(it & 1) * 32768u;
        if (it < 7) { STAGE(src, cur ^ 32768u); src += 32768; }

        const char* bufc = lds0 + cur;
#pragma unroll
        for (int t = 0; t < 2; ++t) {
            f32x4 acc[2][4] = {};
#pragma unroll
            for (int ks = 0; ks < 2; ++ks) {
                short8 bh[4], bl[4];
#pragma unroll
                for (int n = 0; n < 4; ++n) {
                    const int off = t * 16384 + n * 2048 + rowoff + (ks ? swz1 : swz0);
                    bh[n] = *reinterpret_cast<const short8*>(bufc + off);
                    bl[n] = *reinterpret_cast<const short8*>(bufc + 8192 + off);
                }
#pragma unroll
                for (int n = 0; n < 4; ++n)
#pragma unroll
                    for (int m = 0; m < 2; ++m)
                        acc[m][n] = __builtin_amdgcn_mfma_f32_16x16x32_bf16(
                            ks ? Ah[m][1] : Ah[m][0], bh[n], acc[m][n], 0, 0, 0);
#pragma unroll
                for (int n = 0; n < 4; ++n)
#pragma unroll
                    for (int m = 0; m < 2; ++m)
                        acc[m][n] = __builtin_amdgcn_mfma_f32_16x16x32_bf16(
                            ks ? Ah[m][1] : Ah[m][0], bl[n], acc[m][n], 0, 0, 0);
#pragma unroll
                for (int n = 0; n < 4; ++n)
#pragma unroll
                    for (int m = 0; m < 2; ++m)
                        acc[m][n] = __builtin_amdgcn_mfma_f32_16x16x32_bf16(
                            ks ? Al[m][1] : Al[m][0], bh[n], acc[m][n], 0, 0, 0);
            }

#pragma unroll
            for (int n = 0; n < 4; ++n) {
                const int kv = it * 128 + t * 64 + n * 16 + lo;
#pragma unroll
                for (int m = 0; m < 2; ++m)
#pragma unroll
                    for (int q = 0; q < 4; ++q) {
                        const int sidx = m * 4 + q;
                        const float s = fmaf(-2.0f, acc[m][n][q], c2v[t][n]);
                        const bool lt  = s < best[sidx];
                        const bool lt2 = s < b2[sidx];
                        b2[sidx]   = lt ? best[sidx] : (lt2 ? s : b2[sidx]);
                        k2[sidx]   = lt ? bk[sidx]   : (lt2 ? kv : k2[sidx]);
                        best[sidx] = lt ? s : best[sidx];
                        bk[sidx]   = lt ? kv : bk[sidx];
                    }
            }
        }
        __syncthreads();
    }

    // butterfly over the 16 lo-lanes (frozen), 8 streams; publish to winfo
#pragma unroll
    for (int s = 0; s < 8; ++s) {
        const int m = s >> 2, q = s & 3;
        float pb = best[s], p2 = b2[s];
        int   kq = bk[s],   kq2 = k2[s];
#pragma unroll
        for (int st = 1; st < 16; st <<= 1) {
            const float ob  = __shfl_xor(pb, st);
            const int   obk = __shfl_xor(kq, st);
            const float ob2 = __shfl_xor(p2, st);
            const int   ok2 = __shfl_xor(kq2, st);
            const bool bet = (ob < pb) || (ob == pb && obk < kq);
            const float lb  = bet ? pb : ob;
            const int   lk  = bet ? kq : obk;
            const float wb2 = bet ? ob2 : p2;
            const int   wk2 = bet ? ok2 : kq2;
            const bool s2 = (lb < wb2) || (lb == wb2 && lk < wk2);
            p2  = s2 ? lb : wb2;
            kq2 = s2 ? lk : wk2;
            pb  = bet ? ob : pb;
            kq  = bet ? obk : kq;
        }
        if (lo == 0) {
            const int ridx = m * 16 + hi * 4 + q;
            const bool fl = (p2 - pb) <= MARGIN;           // same flag as vq_pick
            winfo[w][ridx] = kq | (kq2 << 10) | (fl ? (1 << 20) : 0);
        }
    }
    __syncthreads();

    // ---- fused pick: per-row rescue + gather + write (vq_pick arithmetic verbatim) ----
    const float* cgrp = cb + (size_t)g * NK * ND;
    float esum = 0.f;
#pragma unroll 1
    for (int r = 0; r < 32; ++r) {
        const int info = winfo[w][r];
        const int row  = rbase + r;
        const float zd = z[(size_t)row * GD + g * ND + lane];
        int win = info & 1023;

        if (info & (1 << 20)) {                    // wave-uniform rescue branch
            const int kalt = (info >> 10) & 1023;
            const float z2 = wredsum(zd * zd);
            const float c1 = cgrp[(size_t)win * ND + lane];
            const float d1 = (z2 + c2g[win]) - 2.0f * wredsum(zd * c1);
            const float c2 = cgrp[(size_t)kalt * ND + lane];
            const float d2 = (z2 + c2g[kalt]) - 2.0f * wredsum(zd * c2);
            if (d2 < d1 || (d2 == d1 && kalt < win)) win = kalt;
        }

        const float cw = cgrp[(size_t)win * ND + lane];
        out[(size_t)row * GD + g * ND + lane] = zd + (cw - zd);
        const float e = zd - cw;
        esum += e * e;

        if (lane == 0) {
            out[(size_t)NB * GD + (size_t)row * NG + g] = (float)win;
            atomicAdd((unsigned*)((char*)ws + WS_HIST_OFF) + win, 1u);
        }
    }

    // commitment partial: per-lane sums -> wave reduce -> block partial
    esum = wredsum(esum);
    __shared__ float sh[4];
    if (lane == 0) sh[w] = esum;
    __syncthreads();
    if (tid == 0)
        ((float*)((char*)ws + WS_PART_OFF))[blockIdx.y * 64 + blockIdx.x] =
            (sh[0] + sh[1]) + (sh[2] + sh[3]);
}

// ---------------- finalize ----------------
__global__ __launch_bounds__(1024) void vq_final(const float* __restrict__ ws,
                                                 float* __restrict__ out) {
    const int t = threadIdx.x;
    __shared__ float se[1024];
    __shared__ float sc[1024];
    const unsigned cnt = ((const unsigned*)((const char*)ws + WS_HIST_OFF))[t];
    const float usage = (float)cnt * (1.0f / 65536.f);
    se[t] = -usage * logf(usage + 1e-10f);
    const float* part = (const float*)((const char*)ws + WS_PART_OFF);
    sc[t] = (t < 512) ? part[t] : 0.f;
    __syncthreads();
    for (int st = 512; st > 0; st >>= 1) {
        if (t < st) {
            se[t] += se[t + st];
            sc[t] += sc[t + st];
        }
        __syncthreads();
    }
    if (t == 0) {
        float* scal = out + (size_t)NB * GD + (size_t)NB * NG;
        scal[0] = sc[0] * (1.0f / ((float)NB * NG * ND));  // commitment_loss
        scal[1] = 0.0f;                                    // codebook_loss
        scal[2] = se[0];                                   // entropy
        scal[3] = expf(se[0]);                             // perplexity
    }
}

extern "C" void kernel_launch(void* const* d_in, const int* in_sizes, int n_in,
                              void* d_out, int out_size, void* d_ws, size_t ws_size,
                              hipStream_t stream) {
    const float* z  = (const float*)d_in[0];
    const float* cb = (const float*)d_in[1];
    float* out = (float*)d_out;
    float* ws  = (float*)d_ws;

    hipLaunchKernelGGL(vq_prep,  dim3(128),   dim3(64),   0, stream, cb, ws);
    hipLaunchKernelGGL(vq_score, dim3(64, 8), dim3(256),  0, stream, z, cb, out, ws);
    hipLaunchKernelGGL(vq_final, dim3(1),     dim3(1024), 0, stream, ws, out);
}